// Round 3
// baseline (27608.578 us; speedup 1.0000x reference)
//
#include <hip/hip_runtime.h>
#include <math.h>

#define BATCH 2048
#define STEPS 512
#define EMB   128
#define HID   256
#define INGRU 641          // EMB + STEPS + 1

// ws layout in float4 units: Wh4 [256 k][256 gd] | Wx4 [128 k][256 gd]
// Each float4 = (w_r, w_z, w_n, 0) for one (k, gd).  Total 1.5 MB.
#define WH4_OFF 0
#define WX4_OFF (256*256)

__global__ void prep_weights(const float* __restrict__ W_ih,
                             const float* __restrict__ W_hh,
                             float4* __restrict__ W4) {
    const int idx = blockIdx.x * 256 + threadIdx.x;   // 256*256 threads
    const int gd = idx & 255;
    const int c  = idx >> 8;
    W4[WH4_OFF + c * 256 + gd] = make_float4(W_hh[gd * HID + c],
                                             W_hh[(HID + gd) * HID + c],
                                             W_hh[(2 * HID + gd) * HID + c], 0.f);
    if (c < 128)
        W4[WX4_OFF + c * 256 + gd] = make_float4(W_ih[gd * INGRU + c],
                                                 W_ih[(HID + gd) * INGRU + c],
                                                 W_ih[(2 * HID + gd) * INGRU + c], 0.f);
}

// Per k: same per-sum fma order as R1 (k ascending for every (row, gate)).
#define FMA2(A0, A1, A2, W, H) do {                                      \
    A0[0] = fmaf(W.x, H.x, A0[0]); A0[1] = fmaf(W.x, H.y, A0[1]);        \
    A1[0] = fmaf(W.y, H.x, A1[0]); A1[1] = fmaf(W.y, H.y, A1[1]);        \
    A2[0] = fmaf(W.z, H.x, A2[0]); A2[1] = fmaf(W.z, H.y, A2[1]);        \
} while (0)

// One WG = 8 batch rows, persistent over all 512 steps.
// 1024 threads: gd = t&255 (gate dim), rg = t>>8 (rows rg*2, rg*2+1).
// Full K per thread -> every gate sum is bit-identical to the R1 kernel.
__global__ __launch_bounds__(1024, 4) void gru_policy(
    const float* __restrict__ X,      // [B][STEPS][EMB]
    const float4* __restrict__ W4,    // packed Wh4 | Wx4
    const float* __restrict__ W_ih,   // raw, for one-hot column gather
    const float* __restrict__ b_ih,   // [768]
    const float* __restrict__ b_hh,   // [768]
    const float* __restrict__ W_cf,   // [2][256]
    const float* __restrict__ b_cf,   // [2]
    float* __restrict__ out)          // [B*STEPS] actions | [B*STEPS] pis
{
    __shared__ __align__(16) float h_lds[2][HID][12];
    __shared__ __align__(16) float x_lds[EMB][12];
    __shared__ float red[16][4];      // [wave][row(j)*2 + class]
    __shared__ int   tag_lds[8];

    const int t    = threadIdx.x;
    const int gd   = t & 255;
    const int rg   = t >> 8;          // 0..3
    const int rg2  = rg * 2;
    const int wv   = t >> 6;          // 0..15
    const int lane = t & 63;
    const size_t r0 = (size_t)blockIdx.x * 8;

    const int xr = t >> 7, xk = t & 127;
    const size_t xbase = (r0 + xr) * (size_t)(STEPS * EMB) + xk;

    const float bi0 = b_ih[gd], bi1 = b_ih[gd + HID], bi2 = b_ih[gd + 2 * HID];
    const float bh0 = b_hh[gd], bh1 = b_hh[gd + HID], bh2 = b_hh[gd + 2 * HID];
    const float wcf0 = W_cf[gd], wcf1 = W_cf[HID + gd];
    const float bc0 = b_cf[0], bc1 = b_cf[1];
    // gather bases: W_ih[g][EMB + tag], g = gd, gd+256, gd+512
    const float* __restrict__ Wg0 = W_ih + (size_t)gd * INGRU + EMB;
    const float* __restrict__ Wg1 = W_ih + (size_t)(HID + gd) * INGRU + EMB;
    const float* __restrict__ Wg2 = W_ih + (size_t)(2 * HID + gd) * INGRU + EMB;

    for (int i = t; i < HID; i += 1024) {
        #pragma unroll
        for (int r = 0; r < 8; ++r) h_lds[0][i][r] = 0.0f;
    }
    x_lds[xk][xr] = X[xbase];
    if (t < 8) tag_lds[t] = 0;
    __syncthreads();

    int cur = 0;
    for (int s = 0; s < STEPS; ++s) {
        // next step's x: issue load now, LDS write after barrier 1
        float xv = 0.0f;
        if (s + 1 < STEPS) xv = X[xbase + (size_t)(s + 1) * EMB];

        // one-hot column gather: issue now, consumed after h-GEMM
        const int tg0 = tag_lds[rg2], tg1 = tag_lds[rg2 + 1];
        const float wc00 = Wg0[tg0], wc01 = Wg0[tg1];
        const float wc10 = Wg1[tg0], wc11 = Wg1[tg1];
        const float wc20 = Wg2[tg0], wc21 = Wg2[tg1];

        // ---- gh = b_hh + h @ W_hh^T  (K = 256, sequential k) ----
        float aH0[2] = {bh0, bh0}, aH1[2] = {bh1, bh1}, aH2[2] = {bh2, bh2};
        {
            const float* hp_ = &h_lds[cur][0][rg2];
            int wi = gd;
            float4 wA = W4[wi]; wi += 256;
            float4 wB = W4[wi]; wi += 256;
            float2 hA = *(const float2*)hp_; hp_ += 12;
            float2 hB = *(const float2*)hp_; hp_ += 12;
            #pragma unroll 4
            for (int k = 0; k < 254; k += 2) {
                const float4 wC = W4[wi]; wi += 256;
                const float4 wD = W4[wi]; wi += 256;
                const float2 hC = *(const float2*)hp_; hp_ += 12;
                const float2 hD = *(const float2*)hp_; hp_ += 12;
                FMA2(aH0, aH1, aH2, wA, hA);
                FMA2(aH0, aH1, aH2, wB, hB);
                wA = wC; wB = wD; hA = hC; hB = hD;
            }
            FMA2(aH0, aH1, aH2, wA, hA);
            FMA2(aH0, aH1, aH2, wB, hB);
        }

        // ---- gi = b_ih + onehot-col + x @ W_ihx^T  (K = 128) ----
        float aI0[2] = {bi0 + wc00, bi0 + wc01};
        float aI1[2] = {bi1 + wc10, bi1 + wc11};
        float aI2[2] = {bi2 + wc20, bi2 + wc21};
        {
            const float* xp_ = &x_lds[0][rg2];
            int wi = WX4_OFF + gd;
            float4 wA = W4[wi]; wi += 256;
            float4 wB = W4[wi]; wi += 256;
            float2 hA = *(const float2*)xp_; xp_ += 12;
            float2 hB = *(const float2*)xp_; xp_ += 12;
            #pragma unroll 4
            for (int k = 0; k < 126; k += 2) {
                const float4 wC = W4[wi]; wi += 256;
                const float4 wD = W4[wi]; wi += 256;
                const float2 hC = *(const float2*)xp_; xp_ += 12;
                const float2 hD = *(const float2*)xp_; xp_ += 12;
                FMA2(aI0, aI1, aI2, wA, hA);
                FMA2(aI0, aI1, aI2, wB, hB);
                wA = wC; wB = wD; hA = hC; hB = hD;
            }
            FMA2(aI0, aI1, aI2, wA, hA);
            FMA2(aI0, aI1, aI2, wB, hB);
        }

        // ---- gates, h_new, classifier partials (R1 formulas) ----
        const float2 hp = *(const float2*)&h_lds[cur][gd][rg2];
        const float hpj[2] = {hp.x, hp.y};
        float p0[2], p1[2], hn[2];
        #pragma unroll
        for (int j = 0; j < 2; ++j) {
            const float rr = 1.0f / (1.0f + expf(-(aI0[j] + aH0[j])));
            const float zz = 1.0f / (1.0f + expf(-(aI1[j] + aH1[j])));
            const float nn = tanhf(aI2[j] + rr * aH2[j]);
            const float h  = (1.0f - zz) * nn + zz * hpj[j];
            hn[j] = h;
            p0[j] = h * wcf0;
            p1[j] = h * wcf1;
        }
        *(float2*)(&h_lds[cur ^ 1][gd][rg2]) = make_float2(hn[0], hn[1]);

        // full 64-lane butterfly (same tree as R1)
        #pragma unroll
        for (int m = 32; m >= 1; m >>= 1) {
            #pragma unroll
            for (int j = 0; j < 2; ++j) {
                p0[j] += __shfl_xor(p0[j], m, 64);
                p1[j] += __shfl_xor(p1[j], m, 64);
            }
        }
        if (lane == 0) {
            red[wv][0] = p0[0]; red[wv][1] = p1[0];
            red[wv][2] = p0[1]; red[wv][3] = p1[1];
        }
        __syncthreads();   // h_new, red visible; all x/h GEMM reads done

        // ---- softmax / argmax / tag update, one thread per row ----
        if (t < 8) {
            const int rgq = t >> 1;   // waves rgq*4..rgq*4+3 hold rows rgq*2,+1
            const int j   = t & 1;
            float l0 = bc0, l1 = bc1;
            #pragma unroll
            for (int w = 0; w < 4; ++w) {         // ascending gd blocks, as R1
                l0 += red[rgq * 4 + w][j * 2];
                l1 += red[rgq * 4 + w][j * 2 + 1];
            }
            const int act = (l1 > l0) ? 1 : 0;
            const float mx = fmaxf(l0, l1);
            const float e0 = expf(l0 - mx), e1 = expf(l1 - mx);
            const float pi = (act ? e1 : e0) / (e0 + e1);
            const size_t row = r0 + t;
            out[row * STEPS + s] = (float)act;
            out[(size_t)BATCH * STEPS + row * STEPS + s] = pi;
            tag_lds[t] += act;
        }

        // write next step's x (old-x reads finished before barrier 1)
        if (s + 1 < STEPS) x_lds[xk][xr] = xv;
        __syncthreads();   // tags + x + h_new ready
        cur ^= 1;
    }
}

extern "C" void kernel_launch(void* const* d_in, const int* in_sizes, int n_in,
                              void* d_out, int out_size, void* d_ws, size_t ws_size,
                              hipStream_t stream) {
    const float* X    = (const float*)d_in[0];
    const float* W_ih = (const float*)d_in[1];
    const float* W_hh = (const float*)d_in[2];
    const float* b_ih = (const float*)d_in[3];
    const float* b_hh = (const float*)d_in[4];
    const float* W_cf = (const float*)d_in[5];
    const float* b_cf = (const float*)d_in[6];
    float* out = (float*)d_out;
    float4* W4 = (float4*)d_ws;

    prep_weights<<<256, 256, 0, stream>>>(W_ih, W_hh, W4);
    gru_policy<<<BATCH / 8, 1024, 0, stream>>>(X, W4, W_ih, b_ih, b_hh,
                                               W_cf, b_cf, out);
}

// Round 4
// 12140.362 us; speedup vs baseline: 2.2741x; 2.2741x over previous
//
#include <hip/hip_runtime.h>
#include <math.h>

#define BATCH 2048
#define STEPS 512
#define EMB   128
#define HID   256
#define INGRU 641          // EMB + STEPS + 1

// ws layout:
//   float4 Whp[64][768]  : Whp[k4][g] = W_hh[g][4k4..4k4+3]
//   float4 Wxp[32][768]  : Wxp[k4][g] = W_ih[g][4k4..4k4+3]
//   float  Wcol[513][768]: Wcol[c][g] = W_ih[g][EMB+c]
#define WHP_OFF  0
#define WXP_OFF  (64*768)                   // float4 index
#define WCOL_OFF ((64+32)*768*4)            // float index = 294912
// total floats = 294912 + 513*768 = 688896  (2.63 MB)

__global__ void prep_weights(const float* __restrict__ W_ih,
                             const float* __restrict__ W_hh,
                             float* __restrict__ ws) {
    const int idx = blockIdx.x * 256 + threadIdx.x;     // < 513*768
    const int g  = idx % 768;
    const int c  = idx / 768;
    float4* __restrict__ Wp = (float4*)ws;
    if (c < 64)    // Whp: 4 consecutive k of W_hh row g (16B-aligned source)
        Wp[WHP_OFF + idx] = *(const float4*)(W_hh + (size_t)g * HID + 4 * c);
    if (c < 32) {  // Wxp (source unaligned: scalar gathers)
        const float* src = W_ih + (size_t)g * INGRU + 4 * c;
        Wp[WXP_OFF + idx] = make_float4(src[0], src[1], src[2], src[3]);
    }
    if (c < 513)   // Wcol
        ws[WCOL_OFF + idx] = W_ih[(size_t)g * INGRU + EMB + c];
}

// 8 fma for one k into the 8 row-accumulators (k-ascending chains preserved)
#define FMA8(ACC, WS, HA, HB) do {                                        \
    ACC[0] = fmaf(WS, HA.x, ACC[0]); ACC[1] = fmaf(WS, HA.y, ACC[1]);     \
    ACC[2] = fmaf(WS, HA.z, ACC[2]); ACC[3] = fmaf(WS, HA.w, ACC[3]);     \
    ACC[4] = fmaf(WS, HB.x, ACC[4]); ACC[5] = fmaf(WS, HB.y, ACC[5]);     \
    ACC[6] = fmaf(WS, HB.z, ACC[6]); ACC[7] = fmaf(WS, HB.w, ACC[7]);     \
} while (0)

// consume one float4 of weights (4 consecutive k), HP = &lds[k0][0], stride 12
#define ACC4(ACC, W, HP) do {                                                          \
    { const float4 hA = *(const float4*)(HP),      hB = *(const float4*)((HP) + 4);    \
      FMA8(ACC, (W).x, hA, hB); }                                                      \
    { const float4 hA = *(const float4*)((HP)+12), hB = *(const float4*)((HP) + 16);   \
      FMA8(ACC, (W).y, hA, hB); }                                                      \
    { const float4 hA = *(const float4*)((HP)+24), hB = *(const float4*)((HP) + 28);   \
      FMA8(ACC, (W).z, hA, hB); }                                                      \
    { const float4 hA = *(const float4*)((HP)+36), hB = *(const float4*)((HP) + 40);   \
      FMA8(ACC, (W).w, hA, hB); }                                                      \
} while (0)

// One WG = 8 batch rows, persistent over 512 steps. 768 threads = one per
// gate-row g (gate = g>>8 in {r,z,n}, dim d = g&255). Each thread computes
// its gate sum for all 8 rows -> weight-read redundancy 1 (1.18 MB/CU/step).
// Gate exchange via LDS keeps formulas/order bit-identical to the R1 kernel.
__global__ __launch_bounds__(768, 1) void gru_policy(
    const float* __restrict__ X,      // [B][STEPS][EMB]
    const float* __restrict__ ws,
    const float* __restrict__ b_ih,   // [768]
    const float* __restrict__ b_hh,   // [768]
    const float* __restrict__ W_cf,   // [2][256]
    const float* __restrict__ b_cf,   // [2]
    float* __restrict__ out)          // [B*STEPS] actions | [B*STEPS] pis
{
    const float4* __restrict__ Wp   = (const float4*)ws;
    const float*  __restrict__ Wcol = ws + WCOL_OFF;

    __shared__ __align__(16) float h_lds[2][HID][12];
    __shared__ __align__(16) float x_lds[EMB][12];
    __shared__ __align__(16) float rn_lds[HID][12];   // rr, then overwritten by nn
    __shared__ __align__(16) float zz_lds[HID][12];
    __shared__ float red[4][8][2];
    __shared__ int   tag_lds[8];

    const int t    = threadIdx.x;     // gate-row g
    const int gate = t >> 8;          // 0=r 1=z 2=n
    const int d    = t & 255;
    const int wv   = t >> 6;          // 0..11 (waves 0-3 are gate 0)
    const int lane = t & 63;
    const size_t r0 = (size_t)blockIdx.x * 8;
    const size_t xstride = (size_t)STEPS * EMB;

    const float bb_i = b_ih[t], bb_h = b_hh[t];
    const float wcf0 = W_cf[d], wcf1 = W_cf[HID + d];
    const float bc0 = b_cf[0], bc1 = b_cf[1];

    // init h=0, x(step 0), tags
    for (int i = t; i < HID * 8; i += 768) h_lds[0][i >> 3][i & 7] = 0.0f;
    {
        int i = t;
        x_lds[i & 127][i >> 7] = X[(r0 + (i >> 7)) * xstride + (i & 127)];
        i = t + 768;
        if (i < 1024)
            x_lds[i & 127][i >> 7] = X[(r0 + (i >> 7)) * xstride + (i & 127)];
    }
    if (t < 8) tag_lds[t] = 0;
    __syncthreads();

    int cur = 0;
    for (int s = 0; s < STEPS; ++s) {
        // ---- loop-top issues: next x, one-hot column gather ----
        float xv0 = 0.f, xv1 = 0.f;
        if (s + 1 < STEPS && t < 512) {
            xv0 = X[(r0 + (t >> 7)) * xstride + (size_t)(s + 1) * EMB + (t & 127)];
            const int i1 = t + 512;
            xv1 = X[(r0 + (i1 >> 7)) * xstride + (size_t)(s + 1) * EMB + (i1 & 127)];
        }
        float wc[8];
        #pragma unroll
        for (int j = 0; j < 8; ++j)
            wc[j] = Wcol[(size_t)tag_lds[j] * 768 + t];   // coalesced per wave

        // ---- gh = b_hh + h @ Whrow  (K=256, k ascending) ----
        float aH[8];
        #pragma unroll
        for (int j = 0; j < 8; ++j) aH[j] = bb_h;
        {
            const float* hb = &h_lds[cur][0][0];
            const float4* wp = Wp + WHP_OFF + t;
            float4 wA = wp[0], wB = wp[768];
            wp += 1536;
            #pragma unroll 2
            for (int it = 0; it < 62; it += 2) {
                const float4 wC = wp[0], wD = wp[768]; wp += 1536;
                ACC4(aH, wA, hb + (it * 4) * 12);
                ACC4(aH, wB, hb + (it * 4 + 4) * 12);
                wA = wC; wB = wD;
            }
            ACC4(aH, wA, hb + 248 * 12);
            ACC4(aH, wB, hb + 252 * 12);
        }
        // ---- gi = b_ih + Wcol[tag] + x @ Wxrow  (K=128) ----
        float aI[8];
        #pragma unroll
        for (int j = 0; j < 8; ++j) aI[j] = bb_i + wc[j];
        {
            const float* xb = &x_lds[0][0];
            const float4* wp = Wp + WXP_OFF + t;
            float4 wA = wp[0], wB = wp[768];
            wp += 1536;
            #pragma unroll 2
            for (int it = 0; it < 30; it += 2) {
                const float4 wC = wp[0], wD = wp[768]; wp += 1536;
                ACC4(aI, wA, xb + (it * 4) * 12);
                ACC4(aI, wB, xb + (it * 4 + 4) * 12);
                wA = wC; wB = wD;
            }
            ACC4(aI, wA, xb + 120 * 12);
            ACC4(aI, wB, xb + 124 * 12);
        }

        // ---- r,z: sigmoid -> LDS ----
        if (gate == 0) {
            #pragma unroll
            for (int j = 0; j < 8; ++j)
                rn_lds[d][j] = 1.0f / (1.0f + expf(-(aI[j] + aH[j])));
        } else if (gate == 1) {
            #pragma unroll
            for (int j = 0; j < 8; ++j)
                zz_lds[d][j] = 1.0f / (1.0f + expf(-(aI[j] + aH[j])));
        }
        __syncthreads();                    // B1: rr, zz ready; x reads done
        // ---- n: tanh(aI2 + rr*aH2) -> LDS (reuse rr slot) ----
        if (gate == 2) {
            #pragma unroll
            for (int j = 0; j < 8; ++j)
                rn_lds[d][j] = tanhf(aI[j] + rn_lds[d][j] * aH[j]);
        }
        if (s + 1 < STEPS && t < 512) {     // stage next x
            x_lds[t & 127][t >> 7] = xv0;
            const int i1 = t + 512;
            x_lds[i1 & 127][i1 >> 7] = xv1;
        }
        __syncthreads();                    // B2: nn, x staged
        // ---- r-threads: h_new, classifier partials, butterfly ----
        if (gate == 0) {
            float p0[8], p1[8];
            #pragma unroll
            for (int j = 0; j < 8; ++j) {
                const float zz = zz_lds[d][j];
                const float nn = rn_lds[d][j];
                const float hp = h_lds[cur][d][j];
                const float h  = (1.0f - zz) * nn + zz * hp;
                h_lds[cur ^ 1][d][j] = h;
                p0[j] = h * wcf0;
                p1[j] = h * wcf1;
            }
            #pragma unroll
            for (int m = 32; m >= 1; m >>= 1) {
                #pragma unroll
                for (int j = 0; j < 8; ++j) {
                    p0[j] += __shfl_xor(p0[j], m, 64);
                    p1[j] += __shfl_xor(p1[j], m, 64);
                }
            }
            if (lane == 0) {
                #pragma unroll
                for (int j = 0; j < 8; ++j) {
                    red[wv][j][0] = p0[j];
                    red[wv][j][1] = p1[j];
                }
            }
        }
        __syncthreads();                    // B3: h_new, red ready
        // ---- softmax / argmax / tag, one thread per row ----
        if (t < 8) {
            float l0 = bc0, l1 = bc1;
            #pragma unroll
            for (int w = 0; w < 4; ++w) {   // ascending gd blocks, as R1
                l0 += red[w][t][0];
                l1 += red[w][t][1];
            }
            const int act = (l1 > l0) ? 1 : 0;
            const float mx = fmaxf(l0, l1);
            const float e0 = expf(l0 - mx), e1 = expf(l1 - mx);
            const float pi = (act ? e1 : e0) / (e0 + e1);
            const size_t row = r0 + t;
            out[row * STEPS + s] = (float)act;
            out[(size_t)BATCH * STEPS + row * STEPS + s] = pi;
            tag_lds[t] += act;
        }
        __syncthreads();                    // B4: tag ready for next gather
        cur ^= 1;
    }
}

extern "C" void kernel_launch(void* const* d_in, const int* in_sizes, int n_in,
                              void* d_out, int out_size, void* d_ws, size_t ws_size,
                              hipStream_t stream) {
    const float* X    = (const float*)d_in[0];
    const float* W_ih = (const float*)d_in[1];
    const float* W_hh = (const float*)d_in[2];
    const float* b_ih = (const float*)d_in[3];
    const float* b_hh = (const float*)d_in[4];
    const float* W_cf = (const float*)d_in[5];
    const float* b_cf = (const float*)d_in[6];
    float* out = (float*)d_out;
    float* ws  = (float*)d_ws;

    prep_weights<<<1539, 256, 0, stream>>>(W_ih, W_hh, ws);  // 513*768 threads
    gru_policy<<<BATCH / 8, 768, 0, stream>>>(X, ws, b_ih, b_hh, W_cf, b_cf, out);
}

// Round 5
// 9243.116 us; speedup vs baseline: 2.9869x; 1.3134x over previous
//
#include <hip/hip_runtime.h>
#include <math.h>

#define BATCH 2048
#define STEPS 512
#define EMB   128
#define HID   256
#define INGRU 641          // EMB + STEPS + 1

// ws layout:
//   float4 Whp[64 k4][256 d][3 g] : Whp[..] = W_hh[g*256+d][4k4..4k4+3]
//   float4 Wxp[32 k4][256 d][3 g] : Wxp[..] = W_ih[g*256+d][4k4..4k4+3]
//   float  Wcol[513 c][768 gg]    : Wcol[c][gg] = W_ih[gg][EMB+c]
#define WXP_OFF  49152                      // float4 index (64*768)
#define WCOL_OFF 294912                     // float index ((49152+24576)*4)
// total floats = 688896 (2.76 MB), same footprint as R1

__global__ void prep_weights(const float* __restrict__ W_ih,
                             const float* __restrict__ W_hh,
                             float* __restrict__ ws) {
    const int idx = blockIdx.x * 256 + threadIdx.x;     // < 513*768
    float4* __restrict__ Wp = (float4*)ws;
    if (idx < 49152) {                 // Whp
        const int k4 = idx / 768, rem = idx % 768;
        const int d = rem / 3, g = rem % 3;
        Wp[idx] = *(const float4*)(W_hh + ((size_t)(g * 256 + d)) * HID + 4 * k4);
    }
    if (idx < 24576) {                 // Wxp (unaligned source rows)
        const int k4 = idx / 768, rem = idx % 768;
        const int d = rem / 3, g = rem % 3;
        const float* src = W_ih + ((size_t)(g * 256 + d)) * INGRU + 4 * k4;
        Wp[WXP_OFF + idx] = make_float4(src[0], src[1], src[2], src[3]);
    }
    if (idx < 513 * 768) {             // Wcol
        const int c = idx / 768, gg = idx % 768;
        ws[WCOL_OFF + (size_t)c * 768 + gg] = W_ih[(size_t)gg * INGRU + EMB + c];
    }
}

// 8 fma into the 8 row-accumulators for one k (k-ascending chains preserved)
#define FMA8(ACC, S, A, B) do {                                           \
    ACC[0] = fmaf(S, (A).x, ACC[0]); ACC[1] = fmaf(S, (A).y, ACC[1]);     \
    ACC[2] = fmaf(S, (A).z, ACC[2]); ACC[3] = fmaf(S, (A).w, ACC[3]);     \
    ACC[4] = fmaf(S, (B).x, ACC[4]); ACC[5] = fmaf(S, (B).y, ACC[5]);     \
    ACC[6] = fmaf(S, (B).z, ACC[6]); ACC[7] = fmaf(S, (B).w, ACC[7]);     \
} while (0)

// one k: broadcast-read 8 rows of h/x, feed all 3 gate accumulators
#define K1(A0, A1, A2, S0, S1, S2, HP, OFF) do {                          \
    const float4 hA = *(const float4*)((HP) + (OFF));                     \
    const float4 hB = *(const float4*)((HP) + (OFF) + 4);                 \
    FMA8(A0, S0, hA, hB); FMA8(A1, S1, hA, hB); FMA8(A2, S2, hA, hB);     \
} while (0)

// one k4 (4 consecutive k) from three packed weight float4s
#define CONS(A0, A1, A2, W0, W1, W2, HP) do {                             \
    K1(A0, A1, A2, (W0).x, (W1).x, (W2).x, HP, 0);                        \
    K1(A0, A1, A2, (W0).y, (W1).y, (W2).y, HP, 12);                       \
    K1(A0, A1, A2, (W0).z, (W1).z, (W2).z, HP, 24);                       \
    K1(A0, A1, A2, (W0).w, (W1).w, (W2).w, HP, 36);                       \
} while (0)

// One WG = 8 batch rows, persistent over 512 steps. 512 threads:
//   waves 0-3 (t<256, d=t)    : h-GEMM (K=256) + gates + classifier
//   waves 4-7 (t>=256, d=t&255): x-GEMM (K=128) + tag gather + x staging
// Each thread owns gates (r,z,n) of dim d for all 8 rows (G=3 register
// reuse -> minimal LDS traffic); weight redundancy per CU stays 1.
// All accumulation chains are bit-identical to the R1 kernel.
__global__ __launch_bounds__(512, 2) void gru_policy(
    const float* __restrict__ X,      // [B][STEPS][EMB]
    const float* __restrict__ ws,
    const float* __restrict__ b_ih,   // [768]
    const float* __restrict__ b_hh,   // [768]
    const float* __restrict__ W_cf,   // [2][256]
    const float* __restrict__ b_cf,   // [2]
    float* __restrict__ out)          // [B*STEPS] actions | [B*STEPS] pis
{
    const float4* __restrict__ Wp   = (const float4*)ws;
    const float*  __restrict__ Wcol = ws + WCOL_OFF;

    __shared__ __align__(16) float h_lds[2][HID][12];   // 24.6 KB
    __shared__ __align__(16) float x_lds[EMB][12];      //  6.1 KB
    __shared__ float ai_lds[3][8][256];                 // 24.6 KB, conflict-free
    __shared__ float red[4][8][2];
    __shared__ int   tag_lds[8];

    const int t    = threadIdx.x;
    const int d    = t & 255;
    const int half = t >> 8;          // 0 = h-duty, 1 = x-duty
    const int wv   = t >> 6;
    const int lane = t & 63;
    const size_t r0 = (size_t)blockIdx.x * 8;
    const size_t xstride = (size_t)STEPS * EMB;

    const float bc0 = b_cf[0], bc1 = b_cf[1];
    float bh0 = 0.f, bh1 = 0.f, bh2 = 0.f, wcf0 = 0.f, wcf1 = 0.f;
    float bi0 = 0.f, bi1 = 0.f, bi2 = 0.f;
    if (half == 0) {
        bh0 = b_hh[d]; bh1 = b_hh[d + 256]; bh2 = b_hh[d + 512];
        wcf0 = W_cf[d]; wcf1 = W_cf[HID + d];
    } else {
        bi0 = b_ih[d]; bi1 = b_ih[d + 256]; bi2 = b_ih[d + 512];
    }

    // init: h=0 (h-waves), x step0 (x-waves), tags
    if (half == 0) {
        const float4 z4 = make_float4(0.f, 0.f, 0.f, 0.f);
        *(float4*)(&h_lds[0][d][0]) = z4;
        *(float4*)(&h_lds[0][d][4]) = z4;
    } else {
        #pragma unroll
        for (int q = 0; q < 4; ++q) {
            const int i = d + 256 * q, row = i >> 7, col = i & 127;
            x_lds[col][row] = X[(r0 + row) * xstride + col];
        }
    }
    if (t < 8) tag_lds[t] = 0;
    __syncthreads();

    int cur = 0;
    for (int s = 0; s < STEPS; ++s) {
        float aH0[8], aH1[8], aH2[8];
        float xv[4];
        if (half == 0) {
            // ---- gh = b_hh + h @ Whrow  (K=256, k ascending) ----
            #pragma unroll
            for (int j = 0; j < 8; ++j) { aH0[j] = bh0; aH1[j] = bh1; aH2[j] = bh2; }
            const float* hb = &h_lds[cur][0][0];
            const float4* wp = Wp + (size_t)d * 3;
            float4 a0 = wp[0], a1 = wp[1], a2 = wp[2]; wp += 768;
            float4 b0 = wp[0], b1 = wp[1], b2 = wp[2]; wp += 768;
            #pragma unroll 2
            for (int it = 0; it < 62; it += 2) {
                const float4 c0 = wp[0], c1 = wp[1], c2 = wp[2]; wp += 768;
                const float4 e0 = wp[0], e1 = wp[1], e2 = wp[2]; wp += 768;
                CONS(aH0, aH1, aH2, a0, a1, a2, hb + it * 48);
                CONS(aH0, aH1, aH2, b0, b1, b2, hb + it * 48 + 48);
                a0 = c0; a1 = c1; a2 = c2; b0 = e0; b1 = e1; b2 = e2;
            }
            CONS(aH0, aH1, aH2, a0, a1, a2, hb + 62 * 48);
            CONS(aH0, aH1, aH2, b0, b1, b2, hb + 63 * 48);
        } else {
            // ---- tag gather + gi = b_ih + Wcol[tag] + x @ Wxrow (K=128) ----
            float aI0[8], aI1[8], aI2[8];
            #pragma unroll
            for (int j = 0; j < 8; ++j) {
                const size_t tg = (size_t)tag_lds[j] * 768;
                aI0[j] = bi0 + Wcol[tg + d];
                aI1[j] = bi1 + Wcol[tg + 256 + d];
                aI2[j] = bi2 + Wcol[tg + 512 + d];
            }
            if (s + 1 < STEPS) {
                #pragma unroll
                for (int q = 0; q < 4; ++q) {
                    const int i = d + 256 * q, row = i >> 7, col = i & 127;
                    xv[q] = X[(r0 + row) * xstride + (size_t)(s + 1) * EMB + col];
                }
            }
            const float* xb = &x_lds[0][0];
            const float4* wq = Wp + WXP_OFF + (size_t)d * 3;
            float4 a0 = wq[0], a1 = wq[1], a2 = wq[2]; wq += 768;
            float4 b0 = wq[0], b1 = wq[1], b2 = wq[2]; wq += 768;
            #pragma unroll 2
            for (int it = 0; it < 30; it += 2) {
                const float4 c0 = wq[0], c1 = wq[1], c2 = wq[2]; wq += 768;
                const float4 e0 = wq[0], e1 = wq[1], e2 = wq[2]; wq += 768;
                CONS(aI0, aI1, aI2, a0, a1, a2, xb + it * 48);
                CONS(aI0, aI1, aI2, b0, b1, b2, xb + it * 48 + 48);
                a0 = c0; a1 = c1; a2 = c2; b0 = e0; b1 = e1; b2 = e2;
            }
            CONS(aI0, aI1, aI2, a0, a1, a2, xb + 30 * 48);
            CONS(aI0, aI1, aI2, b0, b1, b2, xb + 31 * 48);
            // publish aI (conflict-free: consecutive d per (g,j))
            #pragma unroll
            for (int j = 0; j < 8; ++j) {
                ai_lds[0][j][d] = aI0[j];
                ai_lds[1][j][d] = aI1[j];
                ai_lds[2][j][d] = aI2[j];
            }
        }
        __syncthreads();   // B1: aI ready; x reads done

        if (half == 0) {
            // ---- gates, h_new, classifier partials (R1 formulas) ----
            const float4 hpA = *(const float4*)(&h_lds[cur][d][0]);
            const float4 hpB = *(const float4*)(&h_lds[cur][d][4]);
            const float hpj[8] = {hpA.x, hpA.y, hpA.z, hpA.w,
                                  hpB.x, hpB.y, hpB.z, hpB.w};
            float hn[8], p0[8], p1[8];
            #pragma unroll
            for (int j = 0; j < 8; ++j) {
                const float i0 = ai_lds[0][j][d];
                const float i1 = ai_lds[1][j][d];
                const float i2 = ai_lds[2][j][d];
                const float rr = 1.0f / (1.0f + expf(-(i0 + aH0[j])));
                const float zz = 1.0f / (1.0f + expf(-(i1 + aH1[j])));
                const float nn = tanhf(i2 + rr * aH2[j]);
                const float h  = (1.0f - zz) * nn + zz * hpj[j];
                hn[j] = h;
                p0[j] = h * wcf0;
                p1[j] = h * wcf1;
            }
            *(float4*)(&h_lds[cur ^ 1][d][0]) =
                make_float4(hn[0], hn[1], hn[2], hn[3]);
            *(float4*)(&h_lds[cur ^ 1][d][4]) =
                make_float4(hn[4], hn[5], hn[6], hn[7]);
            #pragma unroll
            for (int m = 32; m >= 1; m >>= 1) {
                #pragma unroll
                for (int j = 0; j < 8; ++j) {
                    p0[j] += __shfl_xor(p0[j], m, 64);
                    p1[j] += __shfl_xor(p1[j], m, 64);
                }
            }
            if (lane == 0) {
                #pragma unroll
                for (int j = 0; j < 8; ++j) {
                    red[wv][j][0] = p0[j];
                    red[wv][j][1] = p1[j];
                }
            }
        } else {
            // stage next x (old-x reads finished before B1)
            if (s + 1 < STEPS) {
                #pragma unroll
                for (int q = 0; q < 4; ++q) {
                    const int i = d + 256 * q, row = i >> 7, col = i & 127;
                    x_lds[col][row] = xv[q];
                }
            }
        }
        __syncthreads();   // B2: h_new, red, x staged

        // ---- softmax / argmax / tag, one thread per row ----
        if (t < 8) {
            float l0 = bc0, l1 = bc1;
            #pragma unroll
            for (int w = 0; w < 4; ++w) {     // ascending dim blocks, as R1
                l0 += red[w][t][0];
                l1 += red[w][t][1];
            }
            const int act = (l1 > l0) ? 1 : 0;
            const float mx = fmaxf(l0, l1);
            const float e0 = expf(l0 - mx), e1 = expf(l1 - mx);
            const float pi = (act ? e1 : e0) / (e0 + e1);
            const size_t row = r0 + t;
            out[row * STEPS + s] = (float)act;
            out[(size_t)BATCH * STEPS + row * STEPS + s] = pi;
            tag_lds[t] += act;
        }
        __syncthreads();   // B3: tags ready for next gather
        cur ^= 1;
    }
}

extern "C" void kernel_launch(void* const* d_in, const int* in_sizes, int n_in,
                              void* d_out, int out_size, void* d_ws, size_t ws_size,
                              hipStream_t stream) {
    const float* X    = (const float*)d_in[0];
    const float* W_ih = (const float*)d_in[1];
    const float* W_hh = (const float*)d_in[2];
    const float* b_ih = (const float*)d_in[3];
    const float* b_hh = (const float*)d_in[4];
    const float* W_cf = (const float*)d_in[5];
    const float* b_cf = (const float*)d_in[6];
    float* out = (float*)d_out;
    float* ws  = (float*)d_ws;

    prep_weights<<<1539, 256, 0, stream>>>(W_ih, W_hh, ws);
    gru_policy<<<BATCH / 8, 512, 0, stream>>>(X, ws, b_ih, b_hh, W_cf, b_cf, out);
}